// Round 5
// baseline (212.337 us; speedup 1.0000x reference)
//
#include <hip/hip_runtime.h>
#include <hip/hip_bf16.h>

#define NB 4096
#define NT2 64            // 4096 / 64 row-blocks
#define NOFF 2016         // strict upper-triangular 64x64 tiles (bi<bj)
#define NTILE 2080        // + 64 diagonal tiles
#define NFIN 16           // last-ticket blocks that run the fused final

typedef short v8s __attribute__((ext_vector_type(8)));
typedef float v4f __attribute__((ext_vector_type(4)));

// ws: sq[4096] f32 | cnt[16] int | xb[4096*128] bf16 (1 MB) | Q2[64][4096] float2 (2 MB)
// Q2[b][i]: (num,den) partial for global row i from 64-col block b.
//   b > block(i): row partials of tile (block(i), b)
//   b < block(i): col partials of tile (b, block(i))   (e and mask symmetric)
//   b == block(i): diagonal tile.
// Every slot written exactly once -> no atomics, no init, poison-safe.

__global__ __launch_bounds__(256) void prep_kernel(const float* __restrict__ x,
        float* __restrict__ sq, float* __restrict__ out, int* __restrict__ cnt,
        unsigned short* __restrict__ xb) {
    int tid = threadIdx.x;
    int row = blockIdx.x * 8 + (tid >> 5);   // 32 threads per row
    int lane = tid & 31;
    const float4* xg = (const float4*)x;
    float4 v = xg[row * 32 + lane];
    __hip_bfloat16 h0 = __float2bfloat16(v.x), h1 = __float2bfloat16(v.y);
    __hip_bfloat16 h2 = __float2bfloat16(v.z), h3 = __float2bfloat16(v.w);
    ushort4 u4;
    u4.x = *(unsigned short*)&h0; u4.y = *(unsigned short*)&h1;
    u4.z = *(unsigned short*)&h2; u4.w = *(unsigned short*)&h3;
    ((ushort4*)xb)[row * 32 + lane] = u4;
    float s = v.x * v.x + v.y * v.y + v.z * v.z + v.w * v.w;
    #pragma unroll
    for (int off = 16; off > 0; off >>= 1) s += __shfl_down(s, off);
    if (lane == 0) sq[row] = s;
    if (blockIdx.x == 0 && tid == 0) { out[0] = 0.f; cnt[0] = 0; }
}

// One block per 64x64 upper-triangular tile (2080 blocks, ~37 KB LDS -> 4/CU).
// Proven padded-136 LDS staging + conflict-free ds_read_b128 fragments.
// Fused final: ticketed last-16 blocks gather Q2 after all tiles complete.
__global__ __launch_bounds__(256, 4) void snn64(
        const unsigned short* __restrict__ xb, const int* __restrict__ y,
        const float* __restrict__ sqg, float2* __restrict__ Q2,
        int* __restrict__ cnt, float* __restrict__ out) {
    __shared__ __align__(16) union {
        unsigned short tiles[2 * 64 * 136];   // 34816 B, padded stride 136
        float2 part[2][64][17];               // 17408 B row-partial overlay
    } sm;
    __shared__ float2 part2[2][64];           // [wm][col] column partials
    __shared__ float sqi[64], sqj[64];
    __shared__ int yi[64], yj[64];
    __shared__ int ticket_s;
    __shared__ float wsum[4];

    const int tid = threadIdx.x;
    const int wave = tid >> 6;
    const int lane = tid & 63;
    const int wm = wave >> 1, wn = wave & 1;  // 2x2 waves over 32-row/col halves
    const int lr = lane & 15, q = lane >> 4;

    // tile decode: off-diagonal tiles first, 64 diagonals in the tail
    int k = blockIdx.x, bi, bj;
    if (k >= NOFF) { bi = k - NOFF; bj = bi; }
    else {
        int tt = k, rem = 63; bi = 0;
        while (tt >= rem) { tt -= rem; ++bi; --rem; }
        bj = bi + 1 + tt;
    }
    const int i0 = bi * 64, j0 = bj * 64;
    const bool diag = (bi == bj);
    unsigned short* At = sm.tiles;
    unsigned short* Bt = diag ? At : At + 64 * 136;

    // stage tiles: coalesced 16B chunks
    const v8s* xg = (const v8s*)xb;   // 16 chunks of 8 bf16 per row
    #pragma unroll
    for (int r = 0; r < 4; ++r) {
        int c = r * 256 + tid;
        int row = c >> 4, cc = c & 15;
        *(v8s*)&At[row * 136 + cc * 8] = xg[(i0 + row) * 16 + cc];
        if (!diag)
            *(v8s*)&Bt[row * 136 + cc * 8] = xg[(j0 + row) * 16 + cc];
    }
    if (tid < 64) {
        sqi[tid] = sqg[i0 + tid]; yi[tid] = y[i0 + tid];
        sqj[tid] = sqg[j0 + tid]; yj[tid] = y[j0 + tid];
    }
    __syncthreads();

    v4f acc[2][2];
    #pragma unroll
    for (int mt = 0; mt < 2; ++mt)
        #pragma unroll
        for (int nt = 0; nt < 2; ++nt)
            acc[mt][nt] = (v4f){0.f, 0.f, 0.f, 0.f};
    #pragma unroll
    for (int kk = 0; kk < 4; ++kk) {          // K = 4 x 32
        v8s a0 = *(const v8s*)&At[(wm * 32 + lr) * 136 + kk * 32 + q * 8];
        v8s a1 = *(const v8s*)&At[(wm * 32 + 16 + lr) * 136 + kk * 32 + q * 8];
        v8s b0 = *(const v8s*)&Bt[(wn * 32 + lr) * 136 + kk * 32 + q * 8];
        v8s b1 = *(const v8s*)&Bt[(wn * 32 + 16 + lr) * 136 + kk * 32 + q * 8];
        acc[0][0] = __builtin_amdgcn_mfma_f32_16x16x32_bf16(a0, b0, acc[0][0], 0, 0, 0);
        acc[0][1] = __builtin_amdgcn_mfma_f32_16x16x32_bf16(a0, b1, acc[0][1], 0, 0, 0);
        acc[1][0] = __builtin_amdgcn_mfma_f32_16x16x32_bf16(a1, b0, acc[1][0], 0, 0, 0);
        acc[1][1] = __builtin_amdgcn_mfma_f32_16x16x32_bf16(a1, b1, acc[1][1], 0, 0, 0);
    }
    __syncthreads();   // tiles read done; part overlay may overwrite

    // fused epilogue: dist -> exp -> masked row & col partials
    float sqj_r[2]; int yj_r[2], jgl[2];
    #pragma unroll
    for (int nt = 0; nt < 2; ++nt) {
        int jc = wn * 32 + nt * 16 + lr;
        sqj_r[nt] = sqj[jc]; yj_r[nt] = yj[jc]; jgl[nt] = j0 + jc;
    }
    float cn[2] = {0.f, 0.f}, cd[2] = {0.f, 0.f};
    #pragma unroll
    for (int mt = 0; mt < 2; ++mt)
        #pragma unroll
        for (int r = 0; r < 4; ++r) {
            int rloc = wm * 32 + mt * 16 + q * 4 + r;   // C/D row = q*4+reg
            float si = sqi[rloc]; int yir = yi[rloc]; int ig = i0 + rloc;
            float n = 0.f, d = 0.f;
            #pragma unroll
            for (int nt = 0; nt < 2; ++nt) {
                float dist = fmaxf(si + sqj_r[nt] - 2.f * acc[mt][nt][r], 0.f);
                float e = __builtin_amdgcn_exp2f(dist * -0.014426950408889634f); // exp(-dist/100)
                float me = (yir == yj_r[nt] && ig != jgl[nt]) ? e : 0.f;
                d += e; n += me;
                cd[nt] += e; cn[nt] += me;
            }
            sm.part[wn][rloc][lr] = make_float2(n, d);
        }
    #pragma unroll
    for (int nt = 0; nt < 2; ++nt) {          // col reduce over q bits (16,32)
        float n2 = cn[nt] + __shfl_xor(cn[nt], 16); n2 += __shfl_xor(n2, 32);
        float d2 = cd[nt] + __shfl_xor(cd[nt], 16); d2 += __shfl_xor(d2, 32);
        if (q == 0) part2[wm][wn * 32 + nt * 16 + lr] = make_float2(n2, d2);
    }
    __syncthreads();

    // row partial block-reduce + unique-slot store (coalesced)
    if (tid < 128) {
        int row = tid >> 1, h = tid & 1;
        float sn = 0.f, sd = 0.f;
        #pragma unroll
        for (int c = 0; c < 16; ++c) {
            float2 v = sm.part[h][row][c]; sn += v.x; sd += v.y;
        }
        sn += __shfl_down(sn, 1); sd += __shfl_down(sd, 1);
        if (h == 0) Q2[bj * NB + i0 + row] = make_float2(sn, sd);
    }
    if (!diag && tid < 64) {
        float2 a = part2[0][tid], b = part2[1][tid];
        Q2[bi * NB + j0 + tid] = make_float2(a.x + b.x, a.y + b.y);
    }

    // ---- fused final: last NFIN tickets gather after all tiles complete ----
    __threadfence();                           // release Q2 writes (agent scope)
    if (tid == 0) ticket_s = atomicAdd(cnt, 1);
    __syncthreads();
    if (ticket_s >= NTILE - NFIN) {
        if (tid == 0) {
            while (__hip_atomic_load(cnt, __ATOMIC_RELAXED,
                                     __HIP_MEMORY_SCOPE_AGENT) < NTILE)
                __builtin_amdgcn_s_sleep(2);
        }
        __syncthreads();
        __threadfence();                       // acquire: invalidate stale lines
        int i = (ticket_s - (NTILE - NFIN)) * 256 + tid;   // this thread's row
        float n = 0.f, d = 0.f;
        #pragma unroll 8
        for (int b = 0; b < NT2; ++b) {        // coalesced across threads
            float2 v = Q2[b * NB + i];
            n += v.x; d += v.y;
        }
        float l = -__logf(n / d);
        #pragma unroll
        for (int off = 32; off > 0; off >>= 1) l += __shfl_down(l, off);
        if (lane == 0) wsum[wave] = l;
        __syncthreads();
        if (tid == 0)
            atomicAdd(out, (wsum[0] + wsum[1] + wsum[2] + wsum[3]) * (1.0f / NB));
    }
}

extern "C" void kernel_launch(void* const* d_in, const int* in_sizes, int n_in,
                              void* d_out, int out_size, void* d_ws, size_t ws_size,
                              hipStream_t stream) {
    const float* x = (const float*)d_in[0];
    const int*   y = (const int*)d_in[1];
    float* out = (float*)d_out;
    float* sq  = (float*)d_ws;
    int*   cnt = (int*)(sq + NB);
    unsigned short* xb = (unsigned short*)(sq + NB + 16);
    float2* Q2 = (float2*)(xb + NB * 128);

    prep_kernel<<<NB / 8, 256, 0, stream>>>(x, sq, out, cnt, xb);
    snn64<<<NTILE, 256, 0, stream>>>(xb, y, sq, Q2, cnt, out);
}

// Round 6
// 73.841 us; speedup vs baseline: 2.8756x; 2.8756x over previous
//
#include <hip/hip_runtime.h>
#include <hip/hip_bf16.h>

#define NB 4096
#define NT2 64            // 4096 / 64 row-blocks
#define NOFF 2016         // strict upper-triangular 64x64 tiles (bi<bj)
#define NTILE 2080        // + 64 diagonal tiles

typedef short v8s __attribute__((ext_vector_type(8)));
typedef float v4f __attribute__((ext_vector_type(4)));

// ws: sq[4096] f32 | xb[4096*128] bf16 (1 MB) | Q2[64][4096] float2 (2 MB)
// Q2[b][i]: (num,den) partial for global row i from 64-col block b.
//   b > block(i): row partials of tile (block(i), b)
//   b < block(i): col partials of tile (b, block(i))   (e and mask symmetric)
//   b == block(i): diagonal tile row partials.
// Every slot written exactly once -> no atomics, no init, poison-safe.
// Cross-kernel visibility via kernel boundary (no device fences in-kernel:
// round-5 post-mortem showed per-block __threadfence = L2 writeback storm).

__global__ __launch_bounds__(256) void prep_kernel(const float* __restrict__ x,
        float* __restrict__ sq, float* __restrict__ out,
        unsigned short* __restrict__ xb) {
    int tid = threadIdx.x;
    int row = blockIdx.x * 8 + (tid >> 5);   // 32 threads per row
    int lane = tid & 31;
    const float4* xg = (const float4*)x;
    float4 v = xg[row * 32 + lane];
    __hip_bfloat16 h0 = __float2bfloat16(v.x), h1 = __float2bfloat16(v.y);
    __hip_bfloat16 h2 = __float2bfloat16(v.z), h3 = __float2bfloat16(v.w);
    ushort4 u4;
    u4.x = *(unsigned short*)&h0; u4.y = *(unsigned short*)&h1;
    u4.z = *(unsigned short*)&h2; u4.w = *(unsigned short*)&h3;
    ((ushort4*)xb)[row * 32 + lane] = u4;
    float s = v.x * v.x + v.y * v.y + v.z * v.z + v.w * v.w;
    #pragma unroll
    for (int off = 16; off > 0; off >>= 1) s += __shfl_down(s, off);
    if (lane == 0) sq[row] = s;
    if (blockIdx.x == 0 && tid == 0) out[0] = 0.f;
}

// One block per 64x64 upper-triangular tile (2080 blocks, ~37 KB LDS -> 4/CU).
// Padded-136 LDS staging + conflict-light ds_read_b128 fragments.
__global__ __launch_bounds__(256, 4) void snn64(
        const unsigned short* __restrict__ xb, const int* __restrict__ y,
        const float* __restrict__ sqg, float2* __restrict__ Q2) {
    __shared__ __align__(16) union {
        unsigned short tiles[2 * 64 * 136];   // 34816 B, padded stride 136
        float2 part[2][64][17];               // 17408 B row-partial overlay
    } sm;
    __shared__ float2 part2[2][64];           // [wm][col] column partials
    __shared__ float sqi[64], sqj[64];
    __shared__ int yi[64], yj[64];

    const int tid = threadIdx.x;
    const int wave = tid >> 6;
    const int lane = tid & 63;
    const int wm = wave >> 1, wn = wave & 1;  // 2x2 waves over 32-row/col halves
    const int lr = lane & 15, q = lane >> 4;

    // tile decode: off-diagonal tiles first, 64 diagonals in the tail
    int k = blockIdx.x, bi, bj;
    if (k >= NOFF) { bi = k - NOFF; bj = bi; }
    else {
        int tt = k, rem = 63; bi = 0;
        while (tt >= rem) { tt -= rem; ++bi; --rem; }
        bj = bi + 1 + tt;
    }
    const int i0 = bi * 64, j0 = bj * 64;
    const bool diag = (bi == bj);
    unsigned short* At = sm.tiles;
    unsigned short* Bt = diag ? At : At + 64 * 136;

    // stage tiles: coalesced 16B chunks
    const v8s* xg = (const v8s*)xb;   // 16 chunks of 8 bf16 per row
    #pragma unroll
    for (int r = 0; r < 4; ++r) {
        int c = r * 256 + tid;
        int row = c >> 4, cc = c & 15;
        *(v8s*)&At[row * 136 + cc * 8] = xg[(i0 + row) * 16 + cc];
        if (!diag)
            *(v8s*)&Bt[row * 136 + cc * 8] = xg[(j0 + row) * 16 + cc];
    }
    if (tid < 64) {
        sqi[tid] = sqg[i0 + tid]; yi[tid] = y[i0 + tid];
        sqj[tid] = sqg[j0 + tid]; yj[tid] = y[j0 + tid];
    }
    __syncthreads();

    v4f acc[2][2];
    #pragma unroll
    for (int mt = 0; mt < 2; ++mt)
        #pragma unroll
        for (int nt = 0; nt < 2; ++nt)
            acc[mt][nt] = (v4f){0.f, 0.f, 0.f, 0.f};
    #pragma unroll
    for (int kk = 0; kk < 4; ++kk) {          // K = 4 x 32
        v8s a0 = *(const v8s*)&At[(wm * 32 + lr) * 136 + kk * 32 + q * 8];
        v8s a1 = *(const v8s*)&At[(wm * 32 + 16 + lr) * 136 + kk * 32 + q * 8];
        v8s b0 = *(const v8s*)&Bt[(wn * 32 + lr) * 136 + kk * 32 + q * 8];
        v8s b1 = *(const v8s*)&Bt[(wn * 32 + 16 + lr) * 136 + kk * 32 + q * 8];
        acc[0][0] = __builtin_amdgcn_mfma_f32_16x16x32_bf16(a0, b0, acc[0][0], 0, 0, 0);
        acc[0][1] = __builtin_amdgcn_mfma_f32_16x16x32_bf16(a0, b1, acc[0][1], 0, 0, 0);
        acc[1][0] = __builtin_amdgcn_mfma_f32_16x16x32_bf16(a1, b0, acc[1][0], 0, 0, 0);
        acc[1][1] = __builtin_amdgcn_mfma_f32_16x16x32_bf16(a1, b1, acc[1][1], 0, 0, 0);
    }
    __syncthreads();   // tiles read done; part overlay may overwrite

    // fused epilogue: dist -> exp -> masked row & col partials
    float sqj_r[2]; int yj_r[2], jgl[2];
    #pragma unroll
    for (int nt = 0; nt < 2; ++nt) {
        int jc = wn * 32 + nt * 16 + lr;
        sqj_r[nt] = sqj[jc]; yj_r[nt] = yj[jc]; jgl[nt] = j0 + jc;
    }
    float cn[2] = {0.f, 0.f}, cd[2] = {0.f, 0.f};
    #pragma unroll
    for (int mt = 0; mt < 2; ++mt)
        #pragma unroll
        for (int r = 0; r < 4; ++r) {
            int rloc = wm * 32 + mt * 16 + q * 4 + r;   // C/D row = q*4+reg
            float si = sqi[rloc]; int yir = yi[rloc]; int ig = i0 + rloc;
            float n = 0.f, d = 0.f;
            #pragma unroll
            for (int nt = 0; nt < 2; ++nt) {
                float dist = fmaxf(si + sqj_r[nt] - 2.f * acc[mt][nt][r], 0.f);
                float e = __builtin_amdgcn_exp2f(dist * -0.014426950408889634f); // exp(-dist/100)
                float me = (yir == yj_r[nt] && ig != jgl[nt]) ? e : 0.f;
                d += e; n += me;
                cd[nt] += e; cn[nt] += me;
            }
            sm.part[wn][rloc][lr] = make_float2(n, d);
        }
    #pragma unroll
    for (int nt = 0; nt < 2; ++nt) {          // col reduce over q bits (16,32)
        float n2 = cn[nt] + __shfl_xor(cn[nt], 16); n2 += __shfl_xor(n2, 32);
        float d2 = cd[nt] + __shfl_xor(cd[nt], 16); d2 += __shfl_xor(d2, 32);
        if (q == 0) part2[wm][wn * 32 + nt * 16 + lr] = make_float2(n2, d2);
    }
    __syncthreads();

    // row partial block-reduce + unique-slot store (coalesced)
    if (tid < 128) {
        int row = tid >> 1, h = tid & 1;
        float sn = 0.f, sd = 0.f;
        #pragma unroll
        for (int c = 0; c < 16; ++c) {
            float2 v = sm.part[h][row][c]; sn += v.x; sd += v.y;
        }
        sn += __shfl_down(sn, 1); sd += __shfl_down(sd, 1);
        if (h == 0) Q2[bj * NB + i0 + row] = make_float2(sn, sd);
    }
    if (!diag && tid < 64) {
        float2 a = part2[0][tid], b = part2[1][tid];
        Q2[bi * NB + j0 + tid] = make_float2(a.x + b.x, a.y + b.y);
    }
}

__global__ __launch_bounds__(256) void snn_final(const float2* __restrict__ Q2,
        float* __restrict__ out) {
    __shared__ float wsum[4];
    int i = blockIdx.x * 256 + threadIdx.x;   // this thread's row
    float n = 0.f, d = 0.f;
    #pragma unroll 8
    for (int b = 0; b < NT2; ++b) {           // coalesced across threads
        float2 v = Q2[b * NB + i];
        n += v.x; d += v.y;
    }
    float l = -__logf(n / d);
    #pragma unroll
    for (int off = 32; off > 0; off >>= 1) l += __shfl_down(l, off);
    if ((threadIdx.x & 63) == 0) wsum[threadIdx.x >> 6] = l;
    __syncthreads();
    if (threadIdx.x == 0)
        atomicAdd(out, (wsum[0] + wsum[1] + wsum[2] + wsum[3]) * (1.0f / NB));
}

extern "C" void kernel_launch(void* const* d_in, const int* in_sizes, int n_in,
                              void* d_out, int out_size, void* d_ws, size_t ws_size,
                              hipStream_t stream) {
    const float* x = (const float*)d_in[0];
    const int*   y = (const int*)d_in[1];
    float* out = (float*)d_out;
    float* sq  = (float*)d_ws;
    unsigned short* xb = (unsigned short*)(sq + NB);
    float2* Q2 = (float2*)(xb + NB * 128);

    prep_kernel<<<NB / 8, 256, 0, stream>>>(x, sq, out, xb);
    snn64<<<NTILE, 256, 0, stream>>>(xb, y, sq, Q2);
    snn_final<<<NB / 256, 256, 0, stream>>>(Q2, out);
}